// Round 2
// baseline (4834.019 us; speedup 1.0000x reference)
//
#include <hip/hip_runtime.h>
#include <hip/hip_bf16.h>

// MSA Transformer block: B=1, S=64, L=256, DM=256, DP=128, H=8, HT=4, NO=32
// Round 2: correctness-first, ALL-fp32 pipeline (reference dtype is float32).

#define S_ 64
#define L_ 256
#define DM_ 256
#define DP_ 128
#define H_ 8
#define HT_ 4
#define NO_ 32

// ---------------- layernorm (1 wave per row) ----------------
__global__ void k_ln(const float* __restrict__ src, float* __restrict__ dst,
                     const float* __restrict__ g, const float* __restrict__ bta, int D) {
  int row = blockIdx.x;
  const float* x = src + (size_t)row * D;
  float* y = dst + (size_t)row * D;
  int t = threadIdx.x; // 64
  float v[4];
  int cnt = 0;
  float sum = 0.f;
  for (int e = t; e < D; e += 64) { float xv = x[e]; v[cnt++] = xv; sum += xv; }
  #pragma unroll
  for (int o = 32; o; o >>= 1) sum += __shfl_down(sum, o);
  sum = __shfl(sum, 0);
  float mean = sum / D;
  float var = 0.f;
  for (int k = 0; k < cnt; k++) { float d = v[k] - mean; var += d * d; }
  #pragma unroll
  for (int o = 32; o; o >>= 1) var += __shfl_down(var, o);
  var = __shfl(var, 0);
  float rstd = rsqrtf(var / D + 1e-5f);
  cnt = 0;
  for (int e = t; e < D; e += 64)
    y[e] = (v[cnt++] - mean) * rstd * g[e] + bta[e];
}

// ---------------- tiled matmul: C[M,N] (=|+=) A[M,K] @ W[K,N] + bias ----------------
// 128x64 tile, 256 threads, 8x4 micro-tile. All fp32.
template<int ACC, int RELU>
__global__ void k_matmul(const float* __restrict__ A, const float* __restrict__ W,
                         const float* __restrict__ bias, float* __restrict__ C,
                         int M, int K, int N) {
  __shared__ float As[128][17];
  __shared__ float Bs[16][64];
  int tid = threadIdx.x;
  int tx = tid & 15, ty = tid >> 4;
  int m0 = blockIdx.y * 128, n0 = blockIdx.x * 64;
  float acc[8][4] = {};
  for (int k0 = 0; k0 < K; k0 += 16) {
    for (int e = tid; e < 2048; e += 256) {
      int r = e >> 4, c = e & 15;
      As[r][c] = A[(size_t)(m0 + r) * K + (k0 + c)];
    }
    for (int e = tid; e < 1024; e += 256) {
      int r = e >> 6, c = e & 63;
      int n = n0 + c;
      Bs[r][c] = (n < N) ? W[(size_t)(k0 + r) * N + n] : 0.f;
    }
    __syncthreads();
    #pragma unroll
    for (int kk = 0; kk < 16; kk++) {
      float ra[8], rb[4];
      #pragma unroll
      for (int i2 = 0; i2 < 8; i2++) ra[i2] = As[ty + 16 * i2][kk];
      #pragma unroll
      for (int j = 0; j < 4; j++) rb[j] = Bs[kk][tx + 16 * j];
      #pragma unroll
      for (int i2 = 0; i2 < 8; i2++)
        #pragma unroll
        for (int j = 0; j < 4; j++) acc[i2][j] += ra[i2] * rb[j];
    }
    __syncthreads();
  }
  #pragma unroll
  for (int i2 = 0; i2 < 8; i2++) {
    int m = m0 + ty + 16 * i2;
    #pragma unroll
    for (int j = 0; j < 4; j++) {
      int n = n0 + tx + 16 * j;
      if (n < N) {
        float v = acc[i2][j] + bias[n];
        if (RELU) v = fmaxf(v, 0.f);
        size_t idx = (size_t)m * N + n;
        if (ACC) C[idx] += v; else C[idx] = v;
      }
    }
  }
}

// ---------------- fused attention over one (lead, head) ----------------
// block = 256 threads; K,V staged in LDS (pad 33); per-i softmax + PV.
__global__ void k_attn(const float* __restrict__ qkv, float* __restrict__ out,
                       int n, int dmodel, int tokStride, int leadStride,
                       int otokStride, int oleadStride, float scale) {
  extern __shared__ float lds[];
  float* Ks = lds;              // n*33
  float* Vs = Ks + n * 33;      // n*33
  float* ssh = Vs + n * 33;     // n
  float* red = ssh + n;         // 8
  float* qsh = red + 8;         // 32
  float* psum = qsh + 32;       // 256
  int h = blockIdx.y;
  const float* base = qkv + (size_t)blockIdx.x * leadStride;
  float* obase = out + (size_t)blockIdx.x * oleadStride + h * 32;
  int qoff = h * 32, koff = dmodel + h * 32, voff = 2 * dmodel + h * 32;
  int tid = threadIdx.x;
  int lane = tid & 63, wid = tid >> 6;
  for (int e = tid; e < n * 32; e += 256) {
    int r = e >> 5, c = e & 31;
    Ks[r * 33 + c] = base[(size_t)r * tokStride + koff + c];
    Vs[r * 33 + c] = base[(size_t)r * tokStride + voff + c];
  }
  __syncthreads();
  int ngroups = n >> 5;
  for (int i = 0; i < n; i++) {
    if (tid < 32) qsh[tid] = base[(size_t)i * tokStride + qoff + tid];
    __syncthreads();
    float s = -1e30f;
    if (tid < n) {
      float acc = 0.f;
      #pragma unroll
      for (int d = 0; d < 32; d++) acc += qsh[d] * Ks[tid * 33 + d];
      s = fminf(fmaxf(acc * scale, -50.f), 50.f);
    }
    float m = s;
    #pragma unroll
    for (int o = 32; o; o >>= 1) m = fmaxf(m, __shfl_down(m, o));
    if (lane == 0) red[wid] = m;
    __syncthreads();
    if (tid == 0) red[4] = fmaxf(fmaxf(red[0], red[1]), fmaxf(red[2], red[3]));
    __syncthreads();
    m = red[4];
    float p = (tid < n) ? __expf(s - m) : 0.f;
    float sm = p;
    #pragma unroll
    for (int o = 32; o; o >>= 1) sm += __shfl_down(sm, o);
    if (lane == 0) red[wid] = sm;
    __syncthreads();
    if (tid == 0) red[5] = red[0] + red[1] + red[2] + red[3];
    __syncthreads();
    float inv = 1.f / red[5];
    if (tid < n) ssh[tid] = p * inv;
    __syncthreads();
    if (tid < ngroups * 32) {
      int d = tid & 31, g = tid >> 5;
      const float* vrow = Vs + g * 32 * 33 + d;
      float acc = 0.f;
      #pragma unroll 8
      for (int jj = 0; jj < 32; jj++) acc += ssh[g * 32 + jj] * vrow[jj * 33];
      psum[tid] = acc;
    }
    __syncthreads();
    if (tid < 32) {
      float acc = 0.f;
      for (int g = 0; g < ngroups; g++) acc += psum[g * 32 + tid];
      obase[(size_t)i * otokStride + tid] = acc;
    }
    __syncthreads();
  }
}

// ---------------- fused outer-product-mean + projection ----------------
// block (j_tile of 4, i), 128 threads; pair[i,j,:] += outer(a_i,b_j)/S @ W + bias
__global__ void k_opm(const float* __restrict__ a, const float* __restrict__ b,
                      const float* __restrict__ W, const float* __restrict__ bias,
                      float* __restrict__ pair) {
  const int JT = 4;
  __shared__ float Ash[S_ * NO_];       // 2048
  __shared__ float Bsh[JT][S_ * NO_];   // 4*2048
  __shared__ float Osh[JT][NO_ * NO_];  // 4*1024
  int i = blockIdx.y;
  int j0 = blockIdx.x * JT;
  int tid = threadIdx.x; // 128
  for (int e = tid; e < S_ * NO_; e += 128) {
    int s = e >> 5, c = e & 31;
    Ash[e] = a[((size_t)s * L_ + i) * NO_ + c];
  }
  #pragma unroll
  for (int jt = 0; jt < JT; jt++)
    for (int e = tid; e < S_ * NO_; e += 128) {
      int s = e >> 5, c = e & 31;
      Bsh[jt][e] = b[((size_t)s * L_ + (j0 + jt)) * NO_ + c];
    }
  __syncthreads();
  const float inv = 1.0f / S_;
  for (int e = tid; e < JT * 1024; e += 128) {
    int jt = e >> 10, idx = e & 1023;
    int c = idx >> 5, d = idx & 31;
    float acc = 0.f;
    for (int s = 0; s < S_; s++) acc += Ash[s * 32 + c] * Bsh[jt][s * 32 + d];
    Osh[jt][idx] = acc * inv;
  }
  __syncthreads();
  float accp[JT] = {};
  for (int idx = 0; idx < 1024; idx++) {
    float w = W[(size_t)idx * DP_ + tid];
    #pragma unroll
    for (int jt = 0; jt < JT; jt++) accp[jt] += Osh[jt][idx] * w;
  }
  float bb = bias[tid];
  #pragma unroll
  for (int jt = 0; jt < JT; jt++) {
    size_t pi = ((size_t)i * L_ + (j0 + jt)) * DP_ + tid;
    pair[pi] += accp[jt] + bb;
  }
}

extern "C" void kernel_launch(void* const* d_in, const int* in_sizes, int n_in,
                              void* d_out, int out_size, void* d_ws, size_t ws_size,
                              hipStream_t stream) {
  const float* msa_in    = (const float*)d_in[0];
  const float* pair_in   = (const float*)d_in[1];
  const float* row_ng    = (const float*)d_in[2];
  const float* row_nb    = (const float*)d_in[3];
  const float* row_qkv_w = (const float*)d_in[4];
  const float* row_qkv_b = (const float*)d_in[5];
  const float* row_out_w = (const float*)d_in[6];
  const float* row_out_b = (const float*)d_in[7];
  const float* col_ng    = (const float*)d_in[8];
  const float* col_nb    = (const float*)d_in[9];
  const float* col_qkv_w = (const float*)d_in[10];
  const float* col_qkv_b = (const float*)d_in[11];
  const float* col_out_w = (const float*)d_in[12];
  const float* col_out_b = (const float*)d_in[13];
  const float* ff_ng     = (const float*)d_in[14];
  const float* ff_nb     = (const float*)d_in[15];
  const float* ff_w1     = (const float*)d_in[16];
  const float* ff_b1     = (const float*)d_in[17];
  const float* ff_w2     = (const float*)d_in[18];
  const float* ff_b2     = (const float*)d_in[19];
  const float* op_ng     = (const float*)d_in[20];
  const float* op_nb     = (const float*)d_in[21];
  const float* op_a_w    = (const float*)d_in[22];
  const float* op_a_b    = (const float*)d_in[23];
  const float* op_b_w    = (const float*)d_in[24];
  const float* op_b_b    = (const float*)d_in[25];
  const float* op_out_w  = (const float*)d_in[26];
  const float* op_out_b  = (const float*)d_in[27];
  const float* tri_ng    = (const float*)d_in[28];
  const float* tri_nb    = (const float*)d_in[29];
  const float* tri_qkv_w = (const float*)d_in[30];
  const float* tri_qkv_b = (const float*)d_in[31];
  const float* tri_out_w = (const float*)d_in[32];
  const float* tri_out_b = (const float*)d_in[33];

  const int MT = S_ * L_;   // 16384 msa tokens
  const int PT = L_ * L_;   // 65536 pair tokens

  // ws arena (fp32): msa 4.19M | pair 8.39M | norm/attn alias 8.39M | qkv 16.78M
  // total 37.75M floats = 151 MB
  float* ws     = (float*)d_ws;
  float* msa_f  = ws;
  float* pair_f = msa_f + (size_t)MT * DM_;
  float* na_b   = pair_f + (size_t)PT * DP_;          // norm + attn-out (aliased)
  float* qkv_b  = na_b + (size_t)PT * DP_;            // qkv / ff hidden / opm a,b
  float* a_b    = qkv_b;                              // OPM a (qkv region free then)
  float* b_b    = a_b + (size_t)MT * NO_;

  const float scale = 0.17677669529663687f; // 1/sqrt(32)

  // residual streams (can't mutate inputs)
  hipMemcpyAsync(msa_f, msa_in, (size_t)MT * DM_ * 4, hipMemcpyDeviceToDevice, stream);
  hipMemcpyAsync(pair_f, pair_in, (size_t)PT * DP_ * 4, hipMemcpyDeviceToDevice, stream);

  // ---- 1. row attention (attend over L) ----
  k_ln<<<MT, 64, 0, stream>>>(msa_f, na_b, row_ng, row_nb, DM_);
  k_matmul<0,0><<<dim3(768 / 64, MT / 128), 256, 0, stream>>>(na_b, row_qkv_w, row_qkv_b, qkv_b, MT, DM_, 768);
  {
    int n = L_;
    size_t lds = (size_t)(n * 33 * 2 + n + 8 + 32 + 256) * 4;
    k_attn<<<dim3(S_, H_), 256, lds, stream>>>(qkv_b, na_b, n, DM_, 3 * DM_, L_ * 3 * DM_, DM_, L_ * DM_, scale);
  }
  k_matmul<1,0><<<dim3(DM_ / 64, MT / 128), 256, 0, stream>>>(na_b, row_out_w, row_out_b, msa_f, MT, DM_, DM_);

  // ---- 2. column attention (attend over S) ----
  k_ln<<<MT, 64, 0, stream>>>(msa_f, na_b, col_ng, col_nb, DM_);
  k_matmul<0,0><<<dim3(768 / 64, MT / 128), 256, 0, stream>>>(na_b, col_qkv_w, col_qkv_b, qkv_b, MT, DM_, 768);
  {
    int n = S_;
    size_t lds = (size_t)(n * 33 * 2 + n + 8 + 32 + 256) * 4;
    k_attn<<<dim3(L_, H_), 256, lds, stream>>>(qkv_b, na_b, n, DM_, L_ * 3 * DM_, 3 * DM_, L_ * DM_, DM_, scale);
  }
  k_matmul<1,0><<<dim3(DM_ / 64, MT / 128), 256, 0, stream>>>(na_b, col_out_w, col_out_b, msa_f, MT, DM_, DM_);

  // ---- 3. feed-forward ----
  k_ln<<<MT, 64, 0, stream>>>(msa_f, na_b, ff_ng, ff_nb, DM_);
  k_matmul<0,1><<<dim3(1024 / 64, MT / 128), 256, 0, stream>>>(na_b, ff_w1, ff_b1, qkv_b, MT, DM_, 1024);
  k_matmul<1,0><<<dim3(DM_ / 64, MT / 128), 256, 0, stream>>>(qkv_b, ff_w2, ff_b2, msa_f, MT, 1024, DM_);

  // ---- 4. outer product mean -> pair ----
  k_ln<<<MT, 64, 0, stream>>>(msa_f, na_b, op_ng, op_nb, DM_);
  k_matmul<0,0><<<dim3(1, MT / 128), 256, 0, stream>>>(na_b, op_a_w, op_a_b, a_b, MT, DM_, NO_);
  k_matmul<0,0><<<dim3(1, MT / 128), 256, 0, stream>>>(na_b, op_b_w, op_b_b, b_b, MT, DM_, NO_);
  k_opm<<<dim3(L_ / 4, L_), 128, 0, stream>>>(a_b, b_b, op_out_w, op_out_b, pair_f);

  // ---- 5. triangle attention (attend over last L), 2 lead-chunks ----
  k_ln<<<PT, 64, 0, stream>>>(pair_f, na_b, tri_ng, tri_nb, DP_);
  for (int c = 0; c < 2; c++) {
    const float* nchunk = na_b + (size_t)c * 128 * L_ * DP_;
    float* ochunk = na_b + (size_t)c * 128 * L_ * DP_;
    int Mc = 128 * L_; // 32768 rows
    k_matmul<0,0><<<dim3(384 / 64, Mc / 128), 256, 0, stream>>>(nchunk, tri_qkv_w, tri_qkv_b, qkv_b, Mc, DP_, 384);
    int n = L_;
    size_t lds = (size_t)(n * 33 * 2 + n + 8 + 32 + 256) * 4;
    k_attn<<<dim3(128, HT_), 256, lds, stream>>>(qkv_b, ochunk, n, DP_, 3 * DP_, L_ * 3 * DP_, DP_, L_ * DP_, scale);
  }
  k_matmul<1,0><<<dim3(DP_ / 64, PT / 128), 256, 0, stream>>>(na_b, tri_out_w, tri_out_b, pair_f, PT, DP_, DP_);

  // ---- 6. pack outputs (msa then pair) ----
  hipMemcpyAsync(d_out, msa_f, (size_t)MT * DM_ * 4, hipMemcpyDeviceToDevice, stream);
  hipMemcpyAsync((float*)d_out + (size_t)MT * DM_, pair_f, (size_t)PT * DP_ * 4, hipMemcpyDeviceToDevice, stream);
}

// Round 3
// 2583.153 us; speedup vs baseline: 1.8714x; 1.8714x over previous
//
#include <hip/hip_runtime.h>
#include <hip/hip_bf16.h>

// MSA Transformer block: B=1, S=64, L=256, DM=256, DP=128, H=8, HT=4, NO=32
// Round 3: bf16 MFMA GEMMs everywhere; OPM as two GEMMs; fp32 residuals/attention.

#define S_ 64
#define L_ 256
#define DM_ 256
#define DP_ 128
#define H_ 8
#define HT_ 4
#define NO_ 32

typedef __hip_bfloat16 bf16;
typedef short short8 __attribute__((ext_vector_type(8)));
typedef float floatx4 __attribute__((ext_vector_type(4)));

// ---------------- layernorm (1 wave per row) -> bf16 out ----------------
__global__ void k_ln(const float* __restrict__ src, bf16* __restrict__ dst,
                     const float* __restrict__ g, const float* __restrict__ bta, int D) {
  int row = blockIdx.x;
  const float* x = src + (size_t)row * D;
  bf16* y = dst + (size_t)row * D;
  int t = threadIdx.x; // 64
  float v[4];
  int cnt = 0;
  float sum = 0.f;
  for (int e = t; e < D; e += 64) { float xv = x[e]; v[cnt++] = xv; sum += xv; }
  #pragma unroll
  for (int o = 32; o; o >>= 1) sum += __shfl_down(sum, o);
  sum = __shfl(sum, 0);
  float mean = sum / D;
  float var = 0.f;
  for (int k = 0; k < cnt; k++) { float d = v[k] - mean; var += d * d; }
  #pragma unroll
  for (int o = 32; o; o >>= 1) var += __shfl_down(var, o);
  var = __shfl(var, 0);
  float rstd = rsqrtf(var / D + 1e-5f);
  cnt = 0;
  for (int e = t; e < D; e += 64)
    y[e] = __float2bfloat16((v[cnt++] - mean) * rstd * g[e] + bta[e]);
}

// ---------------- weight transpose+convert: W[K,N] f32 -> Wt[N,K] bf16 ----------------
__global__ void k_wt(const float* __restrict__ W, bf16* __restrict__ Wt, int K, int N) {
  __shared__ float tile[32][33];
  int k0 = blockIdx.x * 32, n0 = blockIdx.y * 32;
  int tid = threadIdx.x; // 256
  for (int e = tid; e < 1024; e += 256) {
    int r = e >> 5, c = e & 31;
    tile[r][c] = W[(size_t)(k0 + r) * N + (n0 + c)];
  }
  __syncthreads();
  for (int e = tid; e < 1024; e += 256) {
    int r = e >> 5, c = e & 31; // r: n-local, c: k-local
    Wt[(size_t)(n0 + r) * K + (k0 + c)] = __float2bfloat16(tile[c][r]);
  }
}

// ---------------- OPM transpose: a_buf[(s*L+i)*32+c] -> a_t[(i*32+c)*64+s] ----------------
__global__ void k_topm(const bf16* __restrict__ in, bf16* __restrict__ out) {
  __shared__ bf16 tile[64][34];
  int i = blockIdx.x; // L_
  int tid = threadIdx.x; // 256
  for (int e = tid; e < 64 * 32; e += 256) {
    int s = e >> 5, c = e & 31;
    tile[s][c] = in[(size_t)s * (L_ * NO_) + i * NO_ + c];
  }
  __syncthreads();
  for (int e = tid; e < 64 * 32; e += 256) {
    int c = e >> 6, s = e & 63;
    out[((size_t)i * NO_ + c) * S_ + s] = tile[s][c];
  }
}

// ---------------- bf16 MFMA GEMM: C[M,N] = A[M,K] @ Wt[N,K]^T * scale + bias ----------------
// BM=BN=128, BK=64, 256 threads (4 waves, 2x2 of 64x64), 16x16x32 MFMA.
// XOR-swizzled LDS: element (r, kg*8+j) at short-offset r*64 + (kg^(r&7))*8 + j.
template<int ACC, int RELU, int OUTBF>
__global__ void k_gemm(const bf16* __restrict__ A, const bf16* __restrict__ Wt,
                       const float* __restrict__ bias, float* __restrict__ Cf,
                       bf16* __restrict__ Cb, int M, int N, int K, float scale) {
  __shared__ short As[128 * 64];
  __shared__ short Bs[128 * 64];
  const int tid = threadIdx.x;
  const int m0 = blockIdx.y * 128, n0 = blockIdx.x * 128;
  const int w = tid >> 6, l = tid & 63;
  const int wm = (w >> 1) * 64, wn = (w & 1) * 64;
  const int lr = l & 15, lk = l >> 4;
  floatx4 acc[4][4] = {};
  const short* Ash = (const short*)A;
  const short* Bsh = (const short*)Wt;
  for (int k0 = 0; k0 < K; k0 += 64) {
    for (int e = tid; e < 1024; e += 256) {
      int r = e >> 3, kg = e & 7;
      short8 v = *(const short8*)(Ash + (size_t)(m0 + r) * K + k0 + kg * 8);
      *(short8*)(&As[r * 64 + ((kg ^ (r & 7)) * 8)]) = v;
    }
    for (int e = tid; e < 1024; e += 256) {
      int r = e >> 3, kg = e & 7;
      int n = n0 + r;
      short8 v = {0, 0, 0, 0, 0, 0, 0, 0};
      if (n < N) v = *(const short8*)(Bsh + (size_t)n * K + k0 + kg * 8);
      *(short8*)(&Bs[r * 64 + ((kg ^ (r & 7)) * 8)]) = v;
    }
    __syncthreads();
    #pragma unroll
    for (int kk = 0; kk < 2; kk++) {
      short8 af[4], bfr[4];
      #pragma unroll
      for (int mi = 0; mi < 4; mi++) {
        int row = wm + mi * 16 + lr;
        int kg = kk * 4 + lk;
        af[mi] = *(const short8*)(&As[row * 64 + ((kg ^ (row & 7)) * 8)]);
      }
      #pragma unroll
      for (int ni = 0; ni < 4; ni++) {
        int row = wn + ni * 16 + lr;
        int kg = kk * 4 + lk;
        bfr[ni] = *(const short8*)(&Bs[row * 64 + ((kg ^ (row & 7)) * 8)]);
      }
      #pragma unroll
      for (int mi = 0; mi < 4; mi++)
        #pragma unroll
        for (int ni = 0; ni < 4; ni++)
          acc[mi][ni] = __builtin_amdgcn_mfma_f32_16x16x32_bf16(af[mi], bfr[ni], acc[mi][ni], 0, 0, 0);
    }
    __syncthreads();
  }
  #pragma unroll
  for (int ni = 0; ni < 4; ni++) {
    int n = n0 + wn + ni * 16 + lr;
    if (n >= N) continue;
    float bv = bias ? bias[n] : 0.f;
    #pragma unroll
    for (int mi = 0; mi < 4; mi++) {
      int mbase = m0 + wm + mi * 16 + lk * 4;
      #pragma unroll
      for (int r = 0; r < 4; r++) {
        float v = acc[mi][ni][r] * scale + bv;
        if (RELU) v = fmaxf(v, 0.f);
        size_t idx = (size_t)(mbase + r) * N + n;
        if (OUTBF) Cb[idx] = __float2bfloat16(v);
        else { if (ACC) Cf[idx] += v; else Cf[idx] = v; }
      }
    }
  }
}

// ---------------- OPM GEMM2: pair[m,d] += gatherA(T) @ Wt + bias ----------------
// A[m=(i_loc*256+j)][k=(c*32+e)] = T[(i_loc*32+c)*8192 + j*32+e]; N=128, K=1024.
__global__ void k_gemm_opm2(const bf16* __restrict__ T, const bf16* __restrict__ Wt,
                            const float* __restrict__ bias, float* __restrict__ Cf,
                            int N, int K) {
  __shared__ short As[128 * 64];
  __shared__ short Bs[128 * 64];
  const int tid = threadIdx.x;
  const int m0 = blockIdx.y * 128, n0 = blockIdx.x * 128;
  const int i_loc = m0 >> 8, j0 = m0 & 255;
  const int w = tid >> 6, l = tid & 63;
  const int wm = (w >> 1) * 64, wn = (w & 1) * 64;
  const int lr = l & 15, lk = l >> 4;
  floatx4 acc[4][4] = {};
  const short* Tsh = (const short*)T;
  const short* Bsh = (const short*)Wt;
  for (int k0 = 0; k0 < K; k0 += 64) {
    for (int e = tid; e < 1024; e += 256) {
      int r = e >> 3, kg = e & 7;
      int k = k0 + kg * 8;
      int c = k >> 5, eo = k & 31;
      short8 v = *(const short8*)(Tsh + (((size_t)(i_loc * 32 + c)) << 13) + (j0 + r) * 32 + eo);
      *(short8*)(&As[r * 64 + ((kg ^ (r & 7)) * 8)]) = v;
    }
    for (int e = tid; e < 1024; e += 256) {
      int r = e >> 3, kg = e & 7;
      int n = n0 + r;
      short8 v = {0, 0, 0, 0, 0, 0, 0, 0};
      if (n < N) v = *(const short8*)(Bsh + (size_t)n * K + k0 + kg * 8);
      *(short8*)(&Bs[r * 64 + ((kg ^ (r & 7)) * 8)]) = v;
    }
    __syncthreads();
    #pragma unroll
    for (int kk = 0; kk < 2; kk++) {
      short8 af[4], bfr[4];
      #pragma unroll
      for (int mi = 0; mi < 4; mi++) {
        int row = wm + mi * 16 + lr;
        int kg = kk * 4 + lk;
        af[mi] = *(const short8*)(&As[row * 64 + ((kg ^ (row & 7)) * 8)]);
      }
      #pragma unroll
      for (int ni = 0; ni < 4; ni++) {
        int row = wn + ni * 16 + lr;
        int kg = kk * 4 + lk;
        bfr[ni] = *(const short8*)(&Bs[row * 64 + ((kg ^ (row & 7)) * 8)]);
      }
      #pragma unroll
      for (int mi = 0; mi < 4; mi++)
        #pragma unroll
        for (int ni = 0; ni < 4; ni++)
          acc[mi][ni] = __builtin_amdgcn_mfma_f32_16x16x32_bf16(af[mi], bfr[ni], acc[mi][ni], 0, 0, 0);
    }
    __syncthreads();
  }
  #pragma unroll
  for (int ni = 0; ni < 4; ni++) {
    int n = n0 + wn + ni * 16 + lr;
    if (n >= N) continue;
    float bv = bias[n];
    #pragma unroll
    for (int mi = 0; mi < 4; mi++) {
      int mbase = m0 + wm + mi * 16 + lk * 4;
      #pragma unroll
      for (int r = 0; r < 4; r++)
        Cf[(size_t)(mbase + r) * N + n] += acc[mi][ni][r] + bv;
    }
  }
}

// ---------------- fused attention over one (lead, head); fp32 in, bf16 out ----------------
__global__ void k_attn(const float* __restrict__ qkv, bf16* __restrict__ out,
                       int n, int dmodel, int tokStride, int leadStride,
                       int otokStride, int oleadStride, float scale) {
  extern __shared__ float lds[];
  float* Ks = lds;              // n*33
  float* Vs = Ks + n * 33;      // n*33
  float* ssh = Vs + n * 33;     // n
  float* red = ssh + n;         // 8
  float* qsh = red + 8;         // 32
  float* psum = qsh + 32;       // 256
  int h = blockIdx.y;
  const float* base = qkv + (size_t)blockIdx.x * leadStride;
  bf16* obase = out + (size_t)blockIdx.x * oleadStride + h * 32;
  int qoff = h * 32, koff = dmodel + h * 32, voff = 2 * dmodel + h * 32;
  int tid = threadIdx.x;
  int lane = tid & 63, wid = tid >> 6;
  for (int e = tid; e < n * 32; e += 256) {
    int r = e >> 5, c = e & 31;
    Ks[r * 33 + c] = base[(size_t)r * tokStride + koff + c];
    Vs[r * 33 + c] = base[(size_t)r * tokStride + voff + c];
  }
  __syncthreads();
  int ngroups = n >> 5;
  for (int i = 0; i < n; i++) {
    if (tid < 32) qsh[tid] = base[(size_t)i * tokStride + qoff + tid];
    __syncthreads();
    float s = -1e30f;
    if (tid < n) {
      float acc = 0.f;
      #pragma unroll
      for (int d = 0; d < 32; d++) acc += qsh[d] * Ks[tid * 33 + d];
      s = fminf(fmaxf(acc * scale, -50.f), 50.f);
    }
    float m = s;
    #pragma unroll
    for (int o = 32; o; o >>= 1) m = fmaxf(m, __shfl_down(m, o));
    if (lane == 0) red[wid] = m;
    __syncthreads();
    if (tid == 0) red[4] = fmaxf(fmaxf(red[0], red[1]), fmaxf(red[2], red[3]));
    __syncthreads();
    m = red[4];
    float p = (tid < n) ? __expf(s - m) : 0.f;
    float sm = p;
    #pragma unroll
    for (int o = 32; o; o >>= 1) sm += __shfl_down(sm, o);
    if (lane == 0) red[wid] = sm;
    __syncthreads();
    if (tid == 0) red[5] = red[0] + red[1] + red[2] + red[3];
    __syncthreads();
    float inv = 1.f / red[5];
    if (tid < n) ssh[tid] = p * inv;
    __syncthreads();
    if (tid < ngroups * 32) {
      int d = tid & 31, g = tid >> 5;
      const float* vrow = Vs + g * 32 * 33 + d;
      float acc = 0.f;
      #pragma unroll 8
      for (int jj = 0; jj < 32; jj++) acc += ssh[g * 32 + jj] * vrow[jj * 33];
      psum[tid] = acc;
    }
    __syncthreads();
    if (tid < 32) {
      float acc = 0.f;
      for (int g = 0; g < ngroups; g++) acc += psum[g * 32 + tid];
      obase[(size_t)i * otokStride + tid] = __float2bfloat16(acc);
    }
    __syncthreads();
  }
}

extern "C" void kernel_launch(void* const* d_in, const int* in_sizes, int n_in,
                              void* d_out, int out_size, void* d_ws, size_t ws_size,
                              hipStream_t stream) {
  const float* msa_in    = (const float*)d_in[0];
  const float* pair_in   = (const float*)d_in[1];
  const float* row_ng    = (const float*)d_in[2];
  const float* row_nb    = (const float*)d_in[3];
  const float* row_qkv_w = (const float*)d_in[4];
  const float* row_qkv_b = (const float*)d_in[5];
  const float* row_out_w = (const float*)d_in[6];
  const float* row_out_b = (const float*)d_in[7];
  const float* col_ng    = (const float*)d_in[8];
  const float* col_nb    = (const float*)d_in[9];
  const float* col_qkv_w = (const float*)d_in[10];
  const float* col_qkv_b = (const float*)d_in[11];
  const float* col_out_w = (const float*)d_in[12];
  const float* col_out_b = (const float*)d_in[13];
  const float* ff_ng     = (const float*)d_in[14];
  const float* ff_nb     = (const float*)d_in[15];
  const float* ff_w1     = (const float*)d_in[16];
  const float* ff_b1     = (const float*)d_in[17];
  const float* ff_w2     = (const float*)d_in[18];
  const float* ff_b2     = (const float*)d_in[19];
  const float* op_ng     = (const float*)d_in[20];
  const float* op_nb     = (const float*)d_in[21];
  const float* op_a_w    = (const float*)d_in[22];
  const float* op_a_b    = (const float*)d_in[23];
  const float* op_b_w    = (const float*)d_in[24];
  const float* op_b_b    = (const float*)d_in[25];
  const float* op_out_w  = (const float*)d_in[26];
  const float* op_out_b  = (const float*)d_in[27];
  const float* tri_ng    = (const float*)d_in[28];
  const float* tri_nb    = (const float*)d_in[29];
  const float* tri_qkv_w = (const float*)d_in[30];
  const float* tri_qkv_b = (const float*)d_in[31];
  const float* tri_out_w = (const float*)d_in[32];
  const float* tri_out_b = (const float*)d_in[33];

  const int MT = S_ * L_;   // 16384
  const int PT = L_ * L_;   // 65536

  // ---- arena (byte offsets) ----
  char* ws = (char*)d_ws;
  float* msa_f  = (float*)(ws);                    // 16 MB
  float* pair_f = (float*)(ws + 16777216);         // 32 MB
  char*  X      = ws + 50331648;                   // 50 MB scratch (qkv f32 / T bf16 / ffh bf16)
  bf16*  ln_b   = (bf16*)(ws + 100663296);         // 16 MB
  bf16*  ao_b   = (bf16*)(ws + 117440512);         // 16 MB
  bf16*  a_buf  = (bf16*)(ws + 134217728);         // 1 MB
  bf16*  b_buf  = (bf16*)(ws + 135266304);         // 1 MB
  bf16*  a_t    = (bf16*)(ws + 136314880);         // 1 MB
  bf16*  b_t    = (bf16*)(ws + 137363456);         // 1 MB
  bf16*  wts    = (bf16*)(ws + 138412032);         // ~2.6 MB

  bf16* row_qkv_wt = wts;                 // 768*256
  bf16* col_qkv_wt = row_qkv_wt + 196608;
  bf16* row_out_wt = col_qkv_wt + 196608; // 256*256
  bf16* col_out_wt = row_out_wt + 65536;
  bf16* ff_w1t     = col_out_wt + 65536;  // 1024*256
  bf16* ff_w2t     = ff_w1t + 262144;     // 256*1024
  bf16* op_a_wt    = ff_w2t + 262144;     // 32*256
  bf16* op_b_wt    = op_a_wt + 8192;
  bf16* op_out_wt  = op_b_wt + 8192;      // 128*1024
  bf16* tri_qkv_wt = op_out_wt + 131072;  // 384*128
  bf16* tri_out_wt = tri_qkv_wt + 49152;  // 128*128

  float* qkv_b = (float*)X;
  bf16*  ffh   = (bf16*)X;
  bf16*  T_b   = (bf16*)X;

  const float scale = 0.17677669529663687f; // 1/sqrt(32)

  // residual streams
  hipMemcpyAsync(msa_f, msa_in, (size_t)MT * DM_ * 4, hipMemcpyDeviceToDevice, stream);
  hipMemcpyAsync(pair_f, pair_in, (size_t)PT * DP_ * 4, hipMemcpyDeviceToDevice, stream);

  // weight transpose+convert (W[K,N] -> Wt[N,K] bf16)
  k_wt<<<dim3(256 / 32, 768 / 32), 256, 0, stream>>>(row_qkv_w, row_qkv_wt, 256, 768);
  k_wt<<<dim3(256 / 32, 768 / 32), 256, 0, stream>>>(col_qkv_w, col_qkv_wt, 256, 768);
  k_wt<<<dim3(256 / 32, 256 / 32), 256, 0, stream>>>(row_out_w, row_out_wt, 256, 256);
  k_wt<<<dim3(256 / 32, 256 / 32), 256, 0, stream>>>(col_out_w, col_out_wt, 256, 256);
  k_wt<<<dim3(256 / 32, 1024 / 32), 256, 0, stream>>>(ff_w1, ff_w1t, 256, 1024);
  k_wt<<<dim3(1024 / 32, 256 / 32), 256, 0, stream>>>(ff_w2, ff_w2t, 1024, 256);
  k_wt<<<dim3(256 / 32, 32 / 32), 256, 0, stream>>>(op_a_w, op_a_wt, 256, 32);
  k_wt<<<dim3(256 / 32, 32 / 32), 256, 0, stream>>>(op_b_w, op_b_wt, 256, 32);
  k_wt<<<dim3(1024 / 32, 128 / 32), 256, 0, stream>>>(op_out_w, op_out_wt, 1024, 128);
  k_wt<<<dim3(128 / 32, 384 / 32), 256, 0, stream>>>(tri_qkv_w, tri_qkv_wt, 128, 384);
  k_wt<<<dim3(128 / 32, 128 / 32), 256, 0, stream>>>(tri_out_w, tri_out_wt, 128, 128);

  // ---- 1. row attention (attend over L) ----
  k_ln<<<MT, 64, 0, stream>>>(msa_f, ln_b, row_ng, row_nb, DM_);
  k_gemm<0,0,0><<<dim3(6, 128), 256, 0, stream>>>(ln_b, row_qkv_wt, row_qkv_b, qkv_b, nullptr, MT, 768, 256, 1.f);
  {
    size_t lds = (size_t)(L_ * 33 * 2 + L_ + 8 + 32 + 256) * 4;
    k_attn<<<dim3(S_, H_), 256, lds, stream>>>(qkv_b, ao_b, L_, DM_, 768, L_ * 768, DM_, L_ * DM_, scale);
  }
  k_gemm<1,0,0><<<dim3(2, 128), 256, 0, stream>>>(ao_b, row_out_wt, row_out_b, msa_f, nullptr, MT, DM_, DM_, 1.f);

  // ---- 2. column attention (attend over S) ----
  k_ln<<<MT, 64, 0, stream>>>(msa_f, ln_b, col_ng, col_nb, DM_);
  k_gemm<0,0,0><<<dim3(6, 128), 256, 0, stream>>>(ln_b, col_qkv_wt, col_qkv_b, qkv_b, nullptr, MT, 768, 256, 1.f);
  {
    size_t lds = (size_t)(S_ * 33 * 2 + S_ + 8 + 32 + 256) * 4;
    k_attn<<<dim3(L_, H_), 256, lds, stream>>>(qkv_b, ao_b, S_, DM_, L_ * 768, 768, L_ * DM_, DM_, scale);
  }
  k_gemm<1,0,0><<<dim3(2, 128), 256, 0, stream>>>(ao_b, col_out_wt, col_out_b, msa_f, nullptr, MT, DM_, DM_, 1.f);

  // ---- 3. feed-forward ----
  k_ln<<<MT, 64, 0, stream>>>(msa_f, ln_b, ff_ng, ff_nb, DM_);
  k_gemm<0,1,1><<<dim3(8, 128), 256, 0, stream>>>(ln_b, ff_w1t, ff_b1, nullptr, ffh, MT, 1024, 256, 1.f);
  k_gemm<1,0,0><<<dim3(2, 128), 256, 0, stream>>>(ffh, ff_w2t, ff_b2, msa_f, nullptr, MT, DM_, 1024, 1.f);

  // ---- 4. outer product mean -> pair ----
  k_ln<<<MT, 64, 0, stream>>>(msa_f, ln_b, op_ng, op_nb, DM_);
  k_gemm<0,0,1><<<dim3(1, 128), 256, 0, stream>>>(ln_b, op_a_wt, op_a_b, nullptr, a_buf, MT, NO_, DM_, 1.f);
  k_gemm<0,0,1><<<dim3(1, 128), 256, 0, stream>>>(ln_b, op_b_wt, op_b_b, nullptr, b_buf, MT, NO_, DM_, 1.f);
  k_topm<<<L_, 256, 0, stream>>>(a_buf, a_t);
  k_topm<<<L_, 256, 0, stream>>>(b_buf, b_t);
  for (int c = 0; c < 4; c++) {
    // GEMM1: T[(i,c),(j,e)] = (1/S) * a_t_chunk @ b_t^T  (M=2048, N=8192, K=64)
    k_gemm<0,0,1><<<dim3(64, 16), 256, 0, stream>>>(a_t + (size_t)c * 2048 * 64, b_t, nullptr,
                                                    nullptr, T_b, 2048, 8192, 64, 1.f / 64.f);
    // GEMM2: pair_chunk += gather(T) @ op_out_wt + bias (M=16384, N=128, K=1024)
    k_gemm_opm2<<<dim3(1, 128), 256, 0, stream>>>(T_b, op_out_wt, op_out_b,
                                                  pair_f + (size_t)c * 64 * L_ * DP_, DP_, 1024);
  }

  // ---- 5. triangle attention (attend over last L), 2 lead-chunks ----
  k_ln<<<PT, 64, 0, stream>>>(pair_f, ln_b, tri_ng, tri_nb, DP_);
  for (int c = 0; c < 2; c++) {
    int Mc = 128 * L_; // 32768
    k_gemm<0,0,0><<<dim3(3, 256), 256, 0, stream>>>(ln_b + (size_t)c * Mc * DP_, tri_qkv_wt, tri_qkv_b,
                                                    qkv_b, nullptr, Mc, 384, DP_, 1.f);
    size_t lds = (size_t)(L_ * 33 * 2 + L_ + 8 + 32 + 256) * 4;
    k_attn<<<dim3(128, HT_), 256, lds, stream>>>(qkv_b, ao_b + (size_t)c * Mc * DP_, L_, DP_,
                                                 384, L_ * 384, DP_, L_ * DP_, scale);
  }
  k_gemm<1,0,0><<<dim3(1, 512), 256, 0, stream>>>(ao_b, tri_out_wt, tri_out_b, pair_f, nullptr, PT, DP_, DP_, 1.f);

  // ---- 6. pack outputs (msa then pair) ----
  hipMemcpyAsync(d_out, msa_f, (size_t)MT * DM_ * 4, hipMemcpyDeviceToDevice, stream);
  hipMemcpyAsync((float*)d_out + (size_t)MT * DM_, pair_f, (size_t)PT * DP_ * 4, hipMemcpyDeviceToDevice, stream);
}

// Round 5
// 806.730 us; speedup vs baseline: 5.9921x; 3.2020x over previous
//
#include <hip/hip_runtime.h>
#include <hip/hip_bf16.h>

// MSA Transformer block: B=1, S=64, L=256, DM=256, DP=128, H=8, HT=4, NO=32
// Round 5: MFMA attention (in-register softmax), bf16 qkv, everything MFMA.
// (round-4 fix: no .data access on __hip_bfloat16; manual RNE f32->bf16 bits)

#define S_ 64
#define L_ 256
#define DM_ 256
#define DP_ 128
#define H_ 8
#define HT_ 4
#define NO_ 32

typedef __hip_bfloat16 bf16;
typedef short short8 __attribute__((ext_vector_type(8)));
typedef float floatx4 __attribute__((ext_vector_type(4)));

__device__ __forceinline__ short f2bfs(float x) {
  union { float f; unsigned u; } v;
  v.f = x;
  unsigned r = (v.u + 0x7fffu + ((v.u >> 16) & 1u)) >> 16;
  return (short)r;
}

// ---------------- layernorm (1 wave per row) -> bf16 out ----------------
__global__ void k_ln(const float* __restrict__ src, bf16* __restrict__ dst,
                     const float* __restrict__ g, const float* __restrict__ bta, int D) {
  int row = blockIdx.x;
  const float* x = src + (size_t)row * D;
  bf16* y = dst + (size_t)row * D;
  int t = threadIdx.x; // 64
  float v[4];
  int cnt = 0;
  float sum = 0.f;
  for (int e = t; e < D; e += 64) { float xv = x[e]; v[cnt++] = xv; sum += xv; }
  #pragma unroll
  for (int o = 32; o; o >>= 1) sum += __shfl_down(sum, o);
  sum = __shfl(sum, 0);
  float mean = sum / D;
  float var = 0.f;
  for (int k = 0; k < cnt; k++) { float d = v[k] - mean; var += d * d; }
  #pragma unroll
  for (int o = 32; o; o >>= 1) var += __shfl_down(var, o);
  var = __shfl(var, 0);
  float rstd = rsqrtf(var / D + 1e-5f);
  cnt = 0;
  for (int e = t; e < D; e += 64)
    y[e] = __float2bfloat16((v[cnt++] - mean) * rstd * g[e] + bta[e]);
}

// ---------------- weight transpose+convert: W[K,N] f32 -> Wt[N,K] bf16 ----------------
__global__ void k_wt(const float* __restrict__ W, bf16* __restrict__ Wt, int K, int N) {
  __shared__ float tile[32][33];
  int k0 = blockIdx.x * 32, n0 = blockIdx.y * 32;
  int tid = threadIdx.x; // 256
  for (int e = tid; e < 1024; e += 256) {
    int r = e >> 5, c = e & 31;
    tile[r][c] = W[(size_t)(k0 + r) * N + (n0 + c)];
  }
  __syncthreads();
  for (int e = tid; e < 1024; e += 256) {
    int r = e >> 5, c = e & 31;
    Wt[(size_t)(n0 + r) * K + (k0 + c)] = __float2bfloat16(tile[c][r]);
  }
}

// ---------------- OPM transpose: a_buf[(s*L+i)*32+c] -> a_t[(i*32+c)*64+s] ----------------
__global__ void k_topm(const bf16* __restrict__ in, bf16* __restrict__ out) {
  __shared__ bf16 tile[64][34];
  int i = blockIdx.x; // L_
  int tid = threadIdx.x; // 256
  for (int e = tid; e < 64 * 32; e += 256) {
    int s = e >> 5, c = e & 31;
    tile[s][c] = in[(size_t)s * (L_ * NO_) + i * NO_ + c];
  }
  __syncthreads();
  for (int e = tid; e < 64 * 32; e += 256) {
    int c = e >> 6, s = e & 63;
    out[((size_t)i * NO_ + c) * S_ + s] = tile[s][c];
  }
}

// ---------------- bf16 MFMA GEMM: C[M,N] = A[M,K] @ Wt[N,K]^T * scale + bias ----------------
template<int ACC, int RELU, int OUTBF>
__global__ void k_gemm(const bf16* __restrict__ A, const bf16* __restrict__ Wt,
                       const float* __restrict__ bias, float* __restrict__ Cf,
                       bf16* __restrict__ Cb, int M, int N, int K, float scale) {
  __shared__ short As[128 * 64];
  __shared__ short Bs[128 * 64];
  const int tid = threadIdx.x;
  const int m0 = blockIdx.y * 128, n0 = blockIdx.x * 128;
  const int w = tid >> 6, l = tid & 63;
  const int wm = (w >> 1) * 64, wn = (w & 1) * 64;
  const int lr = l & 15, lk = l >> 4;
  floatx4 acc[4][4] = {};
  const short* Ash = (const short*)A;
  const short* Bsh = (const short*)Wt;
  for (int k0 = 0; k0 < K; k0 += 64) {
    for (int e = tid; e < 1024; e += 256) {
      int r = e >> 3, kg = e & 7;
      short8 v = *(const short8*)(Ash + (size_t)(m0 + r) * K + k0 + kg * 8);
      *(short8*)(&As[r * 64 + ((kg ^ (r & 7)) * 8)]) = v;
    }
    for (int e = tid; e < 1024; e += 256) {
      int r = e >> 3, kg = e & 7;
      int n = n0 + r;
      short8 v = {0, 0, 0, 0, 0, 0, 0, 0};
      if (n < N) v = *(const short8*)(Bsh + (size_t)n * K + k0 + kg * 8);
      *(short8*)(&Bs[r * 64 + ((kg ^ (r & 7)) * 8)]) = v;
    }
    __syncthreads();
    #pragma unroll
    for (int kk = 0; kk < 2; kk++) {
      short8 af[4], bfr[4];
      #pragma unroll
      for (int mi = 0; mi < 4; mi++) {
        int row = wm + mi * 16 + lr;
        int kg = kk * 4 + lk;
        af[mi] = *(const short8*)(&As[row * 64 + ((kg ^ (row & 7)) * 8)]);
      }
      #pragma unroll
      for (int ni = 0; ni < 4; ni++) {
        int row = wn + ni * 16 + lr;
        int kg = kk * 4 + lk;
        bfr[ni] = *(const short8*)(&Bs[row * 64 + ((kg ^ (row & 7)) * 8)]);
      }
      #pragma unroll
      for (int mi = 0; mi < 4; mi++)
        #pragma unroll
        for (int ni = 0; ni < 4; ni++)
          acc[mi][ni] = __builtin_amdgcn_mfma_f32_16x16x32_bf16(af[mi], bfr[ni], acc[mi][ni], 0, 0, 0);
    }
    __syncthreads();
  }
  #pragma unroll
  for (int ni = 0; ni < 4; ni++) {
    int n = n0 + wn + ni * 16 + lr;
    if (n >= N) continue;
    float bv = bias ? bias[n] : 0.f;
    #pragma unroll
    for (int mi = 0; mi < 4; mi++) {
      int mbase = m0 + wm + mi * 16 + lk * 4;
      #pragma unroll
      for (int r = 0; r < 4; r++) {
        float v = acc[mi][ni][r] * scale + bv;
        if (RELU) v = fmaxf(v, 0.f);
        size_t idx = (size_t)(mbase + r) * N + n;
        if (OUTBF) Cb[idx] = __float2bfloat16(v);
        else { if (ACC) Cf[idx] += v; else Cf[idx] = v; }
      }
    }
  }
}

// ---------------- OPM GEMM2: pair[m,d] += gatherA(T) @ Wt + bias ----------------
__global__ void k_gemm_opm2(const bf16* __restrict__ T, const bf16* __restrict__ Wt,
                            const float* __restrict__ bias, float* __restrict__ Cf,
                            int N, int K) {
  __shared__ short As[128 * 64];
  __shared__ short Bs[128 * 64];
  const int tid = threadIdx.x;
  const int m0 = blockIdx.y * 128, n0 = blockIdx.x * 128;
  const int i_loc = m0 >> 8, j0 = m0 & 255;
  const int w = tid >> 6, l = tid & 63;
  const int wm = (w >> 1) * 64, wn = (w & 1) * 64;
  const int lr = l & 15, lk = l >> 4;
  floatx4 acc[4][4] = {};
  const short* Tsh = (const short*)T;
  const short* Bsh = (const short*)Wt;
  for (int k0 = 0; k0 < K; k0 += 64) {
    for (int e = tid; e < 1024; e += 256) {
      int r = e >> 3, kg = e & 7;
      int k = k0 + kg * 8;
      int c = k >> 5, eo = k & 31;
      short8 v = *(const short8*)(Tsh + (((size_t)(i_loc * 32 + c)) << 13) + (j0 + r) * 32 + eo);
      *(short8*)(&As[r * 64 + ((kg ^ (r & 7)) * 8)]) = v;
    }
    for (int e = tid; e < 1024; e += 256) {
      int r = e >> 3, kg = e & 7;
      int n = n0 + r;
      short8 v = {0, 0, 0, 0, 0, 0, 0, 0};
      if (n < N) v = *(const short8*)(Bsh + (size_t)n * K + k0 + kg * 8);
      *(short8*)(&Bs[r * 64 + ((kg ^ (r & 7)) * 8)]) = v;
    }
    __syncthreads();
    #pragma unroll
    for (int kk = 0; kk < 2; kk++) {
      short8 af[4], bfr[4];
      #pragma unroll
      for (int mi = 0; mi < 4; mi++) {
        int row = wm + mi * 16 + lr;
        int kg = kk * 4 + lk;
        af[mi] = *(const short8*)(&As[row * 64 + ((kg ^ (row & 7)) * 8)]);
      }
      #pragma unroll
      for (int ni = 0; ni < 4; ni++) {
        int row = wn + ni * 16 + lr;
        int kg = kk * 4 + lk;
        bfr[ni] = *(const short8*)(&Bs[row * 64 + ((kg ^ (row & 7)) * 8)]);
      }
      #pragma unroll
      for (int mi = 0; mi < 4; mi++)
        #pragma unroll
        for (int ni = 0; ni < 4; ni++)
          acc[mi][ni] = __builtin_amdgcn_mfma_f32_16x16x32_bf16(af[mi], bfr[ni], acc[mi][ni], 0, 0, 0);
    }
    __syncthreads();
  }
  #pragma unroll
  for (int ni = 0; ni < 4; ni++) {
    int n = n0 + wn + ni * 16 + lr;
    if (n >= N) continue;
    float bv = bias[n];
    #pragma unroll
    for (int mi = 0; mi < 4; mi++) {
      int mbase = m0 + wm + mi * 16 + lk * 4;
      #pragma unroll
      for (int r = 0; r < 4; r++)
        Cf[(size_t)(mbase + r) * N + n] += acc[mi][ni][r] + bv;
    }
  }
}

// ---------------- MFMA attention: one (lead, head, 64-row chunk) per block ----------------
// N = sequence length (64 or 256). qkv bf16 [lead][tok][3*dmodel]; out bf16.
// LDS subtiled layouts: Ks[kslot][N][8], Qs[kslot][64][8], Vt[kstep][kslot][32][8],
// P[kstep][kslot][64][8] aliases Ks+Qs (dead after S phase).
template<int N>
__global__ __launch_bounds__(256) void k_attn_mfma(
    const bf16* __restrict__ qkv, bf16* __restrict__ out, int dmodel,
    int tokStride, int leadStride, int otokStride, int oleadStride, float scale) {
  constexpr int NT = N / 16;   // S col-tiles per wave
  constexpr int NK = N / 32;   // PV k-steps
  constexpr int REGA = (64 * N > N * 32 + 2048) ? 64 * N : N * 32 + 2048;
  __shared__ short ldsA[REGA];
  __shared__ short Vt[N * 32];
  short* Ks = ldsA;            // [kslot][N][8]
  short* Qs = ldsA + N * 32;   // [kslot][64][8]
  short* P  = ldsA;            // [kstep][kslot][64][8]

  const int nIC = N / 64;
  const int lead = blockIdx.x / nIC, ic = blockIdx.x - lead * nIC;
  const int h = blockIdx.y;
  const short* base = (const short*)qkv + (size_t)lead * leadStride;
  const int qoff = h * 32, koff = dmodel + h * 32, voff = 2 * dmodel + h * 32;
  const int tid = threadIdx.x;
  const int l = tid & 63, w = tid >> 6;
  const int lr = l & 15, lk = l >> 4;

  // stage K (vector): e -> (row j, kslot kg)
  for (int e = tid; e < N * 4; e += 256) {
    int j = e >> 2, kg = e & 3;
    short8 v = *(const short8*)(base + (size_t)j * tokStride + koff + kg * 8);
    *(short8*)(&Ks[(kg * N + j) * 8]) = v;
  }
  // stage Q chunk (vector)
  for (int e = tid; e < 256; e += 256) {
    int r = e >> 2, kg = e & 3;
    short8 v = *(const short8*)(base + (size_t)(ic * 64 + r) * tokStride + qoff + kg * 8);
    *(short8*)(&Qs[(kg * 64 + r) * 8]) = v;
  }
  // stage V transposed (scalar)
  for (int e = tid; e < N * 32; e += 256) {
    int j = e >> 5, d = e & 31;
    Vt[((j >> 5) * 4 + ((j >> 3) & 3)) * 256 + d * 8 + (j & 7)] = base[(size_t)j * tokStride + voff + d];
  }
  __syncthreads();

  // ---- S = Q @ K^T (per wave: rows w*16..w*16+15) ----
  short8 aq = *(const short8*)(&Qs[(lk * 64 + w * 16 + lr) * 8]);
  floatx4 sa[NT];
  #pragma unroll
  for (int t = 0; t < NT; t++) {
    short8 bk = *(const short8*)(&Ks[(lk * N + t * 16 + lr) * 8]);
    floatx4 z = {0.f, 0.f, 0.f, 0.f};
    sa[t] = __builtin_amdgcn_mfma_f32_16x16x32_bf16(aq, bk, z, 0, 0, 0);
  }

  // ---- in-register softmax (row = w*16 + lk*4 + r, cols = t*16 + lr) ----
  float mrow[4] = {-1e30f, -1e30f, -1e30f, -1e30f};
  #pragma unroll
  for (int t = 0; t < NT; t++)
    #pragma unroll
    for (int r = 0; r < 4; r++) {
      float s = fminf(fmaxf(sa[t][r] * scale, -50.f), 50.f);
      sa[t][r] = s;
      mrow[r] = fmaxf(mrow[r], s);
    }
  #pragma unroll
  for (int o = 1; o <= 8; o <<= 1)
    #pragma unroll
    for (int r = 0; r < 4; r++) mrow[r] = fmaxf(mrow[r], __shfl_xor(mrow[r], o));
  float srow[4] = {0.f, 0.f, 0.f, 0.f};
  #pragma unroll
  for (int t = 0; t < NT; t++)
    #pragma unroll
    for (int r = 0; r < 4; r++) {
      float p = __expf(sa[t][r] - mrow[r]);
      sa[t][r] = p;
      srow[r] += p;
    }
  #pragma unroll
  for (int o = 1; o <= 8; o <<= 1)
    #pragma unroll
    for (int r = 0; r < 4; r++) srow[r] += __shfl_xor(srow[r], o);
  float inv[4];
  #pragma unroll
  for (int r = 0; r < 4; r++) inv[r] = 1.f / srow[r];

  __syncthreads();  // K/Q reads done everywhere; safe to overwrite with P

  // ---- write P bf16 to LDS in A-fragment subtile layout ----
  #pragma unroll
  for (int t = 0; t < NT; t++) {
    int c = t * 16 + lr;
    int kstep = c >> 5, kslot = (c >> 3) & 3, u = c & 7;
    #pragma unroll
    for (int r = 0; r < 4; r++) {
      int row = w * 16 + lk * 4 + r;
      P[((kstep * 4 + kslot) * 64 + row) * 8 + u] = f2bfs(sa[t][r] * inv[r]);
    }
  }
  __syncthreads();

  // ---- O = P @ V ----
  floatx4 oacc[2] = {{0.f,0.f,0.f,0.f},{0.f,0.f,0.f,0.f}};
  #pragma unroll
  for (int ks = 0; ks < NK; ks++) {
    short8 ap = *(const short8*)(&P[((ks * 4 + lk) * 64 + w * 16 + lr) * 8]);
    #pragma unroll
    for (int ct = 0; ct < 2; ct++) {
      short8 bv = *(const short8*)(&Vt[((ks * 4 + lk) * 32 + ct * 16 + lr) * 8]);
      oacc[ct] = __builtin_amdgcn_mfma_f32_16x16x32_bf16(ap, bv, oacc[ct], 0, 0, 0);
    }
  }
  // write out: row = ic*64 + w*16 + lk*4 + r, col = h*32 + ct*16 + lr
  bf16* ob = out + (size_t)lead * oleadStride + h * 32;
  #pragma unroll
  for (int ct = 0; ct < 2; ct++)
    #pragma unroll
    for (int r = 0; r < 4; r++) {
      int tok = ic * 64 + w * 16 + lk * 4 + r;
      ob[(size_t)tok * otokStride + ct * 16 + lr] = __float2bfloat16(oacc[ct][r]);
    }
}

extern "C" void kernel_launch(void* const* d_in, const int* in_sizes, int n_in,
                              void* d_out, int out_size, void* d_ws, size_t ws_size,
                              hipStream_t stream) {
  const float* msa_in    = (const float*)d_in[0];
  const float* pair_in   = (const float*)d_in[1];
  const float* row_ng    = (const float*)d_in[2];
  const float* row_nb    = (const float*)d_in[3];
  const float* row_qkv_w = (const float*)d_in[4];
  const float* row_qkv_b = (const float*)d_in[5];
  const float* row_out_w = (const float*)d_in[6];
  const float* row_out_b = (const float*)d_in[7];
  const float* col_ng    = (const float*)d_in[8];
  const float* col_nb    = (const float*)d_in[9];
  const float* col_qkv_w = (const float*)d_in[10];
  const float* col_qkv_b = (const float*)d_in[11];
  const float* col_out_w = (const float*)d_in[12];
  const float* col_out_b = (const float*)d_in[13];
  const float* ff_ng     = (const float*)d_in[14];
  const float* ff_nb     = (const float*)d_in[15];
  const float* ff_w1     = (const float*)d_in[16];
  const float* ff_b1     = (const float*)d_in[17];
  const float* ff_w2     = (const float*)d_in[18];
  const float* ff_b2     = (const float*)d_in[19];
  const float* op_ng     = (const float*)d_in[20];
  const float* op_nb     = (const float*)d_in[21];
  const float* op_a_w    = (const float*)d_in[22];
  const float* op_a_b    = (const float*)d_in[23];
  const float* op_b_w    = (const float*)d_in[24];
  const float* op_b_b    = (const float*)d_in[25];
  const float* op_out_w  = (const float*)d_in[26];
  const float* op_out_b  = (const float*)d_in[27];
  const float* tri_ng    = (const float*)d_in[28];
  const float* tri_nb    = (const float*)d_in[29];
  const float* tri_qkv_w = (const float*)d_in[30];
  const float* tri_qkv_b = (const float*)d_in[31];
  const float* tri_out_w = (const float*)d_in[32];
  const float* tri_out_b = (const float*)d_in[33];

  const int MT = S_ * L_;   // 16384
  const int PT = L_ * L_;   // 65536

  // ---- arena (byte offsets) ----
  char* ws = (char*)d_ws;
  float* msa_f  = (float*)(ws);                    // 16 MB
  float* pair_f = (float*)(ws + 16777216);         // 32 MB
  char*  X      = ws + 50331648;                   // 48 MB scratch (qkv bf16 / T bf16 / ffh bf16)
  bf16*  ln_b   = (bf16*)(ws + 100663296);         // 16 MB
  bf16*  ao_b   = (bf16*)(ws + 117440512);         // 16 MB
  bf16*  a_buf  = (bf16*)(ws + 134217728);         // 1 MB
  bf16*  b_buf  = (bf16*)(ws + 135266304);         // 1 MB
  bf16*  a_t    = (bf16*)(ws + 136314880);         // 1 MB
  bf16*  b_t    = (bf16*)(ws + 137363456);         // 1 MB
  bf16*  wts    = (bf16*)(ws + 138412032);         // ~2.6 MB

  bf16* row_qkv_wt = wts;                 // 768*256
  bf16* col_qkv_wt = row_qkv_wt + 196608;
  bf16* row_out_wt = col_qkv_wt + 196608; // 256*256
  bf16* col_out_wt = row_out_wt + 65536;
  bf16* ff_w1t     = col_out_wt + 65536;  // 1024*256
  bf16* ff_w2t     = ff_w1t + 262144;     // 256*1024
  bf16* op_a_wt    = ff_w2t + 262144;     // 32*256
  bf16* op_b_wt    = op_a_wt + 8192;
  bf16* op_out_wt  = op_b_wt + 8192;      // 128*1024
  bf16* tri_qkv_wt = op_out_wt + 131072;  // 384*128
  bf16* tri_out_wt = tri_qkv_wt + 49152;  // 128*128

  bf16* qkv_bf = (bf16*)X;   // row/col: MT*768*2=25MB; tri: PT*384*2=48MB (fits exactly)
  bf16* ffh    = (bf16*)X;
  bf16* T_b    = (bf16*)X;

  const float scale = 0.17677669529663687f; // 1/sqrt(32)

  // residual streams
  (void)hipMemcpyAsync(msa_f, msa_in, (size_t)MT * DM_ * 4, hipMemcpyDeviceToDevice, stream);
  (void)hipMemcpyAsync(pair_f, pair_in, (size_t)PT * DP_ * 4, hipMemcpyDeviceToDevice, stream);

  // weight transpose+convert (W[K,N] -> Wt[N,K] bf16)
  k_wt<<<dim3(256 / 32, 768 / 32), 256, 0, stream>>>(row_qkv_w, row_qkv_wt, 256, 768);
  k_wt<<<dim3(256 / 32, 768 / 32), 256, 0, stream>>>(col_qkv_w, col_qkv_wt, 256, 768);
  k_wt<<<dim3(256 / 32, 256 / 32), 256, 0, stream>>>(row_out_w, row_out_wt, 256, 256);
  k_wt<<<dim3(256 / 32, 256 / 32), 256, 0, stream>>>(col_out_w, col_out_wt, 256, 256);
  k_wt<<<dim3(256 / 32, 1024 / 32), 256, 0, stream>>>(ff_w1, ff_w1t, 256, 1024);
  k_wt<<<dim3(1024 / 32, 256 / 32), 256, 0, stream>>>(ff_w2, ff_w2t, 1024, 256);
  k_wt<<<dim3(256 / 32, 32 / 32), 256, 0, stream>>>(op_a_w, op_a_wt, 256, 32);
  k_wt<<<dim3(256 / 32, 32 / 32), 256, 0, stream>>>(op_b_w, op_b_wt, 256, 32);
  k_wt<<<dim3(1024 / 32, 128 / 32), 256, 0, stream>>>(op_out_w, op_out_wt, 1024, 128);
  k_wt<<<dim3(128 / 32, 384 / 32), 256, 0, stream>>>(tri_qkv_w, tri_qkv_wt, 128, 384);
  k_wt<<<dim3(128 / 32, 128 / 32), 256, 0, stream>>>(tri_out_w, tri_out_wt, 128, 128);

  // ---- 1. row attention (attend over L) ----
  k_ln<<<MT, 64, 0, stream>>>(msa_f, ln_b, row_ng, row_nb, DM_);
  k_gemm<0,0,1><<<dim3(6, 128), 256, 0, stream>>>(ln_b, row_qkv_wt, row_qkv_b, nullptr, qkv_bf, MT, 768, 256, 1.f);
  k_attn_mfma<256><<<dim3(256, 8), 256, 0, stream>>>(qkv_bf, ao_b, DM_, 768, L_ * 768, DM_, L_ * DM_, scale);
  k_gemm<1,0,0><<<dim3(2, 128), 256, 0, stream>>>(ao_b, row_out_wt, row_out_b, msa_f, nullptr, MT, DM_, DM_, 1.f);

  // ---- 2. column attention (attend over S) ----
  k_ln<<<MT, 64, 0, stream>>>(msa_f, ln_b, col_ng, col_nb, DM_);
  k_gemm<0,0,1><<<dim3(6, 128), 256, 0, stream>>>(ln_b, col_qkv_wt, col_qkv_b, nullptr, qkv_bf, MT, 768, 256, 1.f);
  k_attn_mfma<64><<<dim3(256, 8), 256, 0, stream>>>(qkv_bf, ao_b, DM_, L_ * 768, 768, L_ * DM_, DM_, scale);
  k_gemm<1,0,0><<<dim3(2, 128), 256, 0, stream>>>(ao_b, col_out_wt, col_out_b, msa_f, nullptr, MT, DM_, DM_, 1.f);

  // ---- 3. feed-forward ----
  k_ln<<<MT, 64, 0, stream>>>(msa_f, ln_b, ff_ng, ff_nb, DM_);
  k_gemm<0,1,1><<<dim3(8, 128), 256, 0, stream>>>(ln_b, ff_w1t, ff_b1, nullptr, ffh, MT, 1024, 256, 1.f);
  k_gemm<1,0,0><<<dim3(2, 128), 256, 0, stream>>>(ffh, ff_w2t, ff_b2, msa_f, nullptr, MT, DM_, 1024, 1.f);

  // ---- 4. outer product mean -> pair ----
  k_ln<<<MT, 64, 0, stream>>>(msa_f, ln_b, op_ng, op_nb, DM_);
  k_gemm<0,0,1><<<dim3(1, 128), 256, 0, stream>>>(ln_b, op_a_wt, op_a_b, nullptr, a_buf, MT, NO_, DM_, 1.f);
  k_gemm<0,0,1><<<dim3(1, 128), 256, 0, stream>>>(ln_b, op_b_wt, op_b_b, nullptr, b_buf, MT, NO_, DM_, 1.f);
  k_topm<<<L_, 256, 0, stream>>>(a_buf, a_t);
  k_topm<<<L_, 256, 0, stream>>>(b_buf, b_t);
  for (int c = 0; c < 4; c++) {
    k_gemm<0,0,1><<<dim3(64, 16), 256, 0, stream>>>(a_t + (size_t)c * 2048 * 64, b_t, nullptr,
                                                    nullptr, T_b, 2048, 8192, 64, 1.f / 64.f);
    k_gemm_opm2<<<dim3(1, 128), 256, 0, stream>>>(T_b, op_out_wt, op_out_b,
                                                  pair_f + (size_t)c * 64 * L_ * DP_, DP_, 1024);
  }

  // ---- 5. triangle attention (attend over last L) ----
  k_ln<<<PT, 64, 0, stream>>>(pair_f, ln_b, tri_ng, tri_nb, DP_);
  k_gemm<0,0,1><<<dim3(3, 512), 256, 0, stream>>>(ln_b, tri_qkv_wt, tri_qkv_b, nullptr, qkv_bf, PT, 384, DP_, 1.f);
  k_attn_mfma<256><<<dim3(1024, 4), 256, 0, stream>>>(qkv_bf, ao_b, DP_, 384, L_ * 384, DP_, L_ * DP_, scale);
  k_gemm<1,0,0><<<dim3(1, 512), 256, 0, stream>>>(ao_b, tri_out_wt, tri_out_b, pair_f, nullptr, PT, DP_, DP_, 1.f);

  // ---- 6. pack outputs (msa then pair) ----
  (void)hipMemcpyAsync(d_out, msa_f, (size_t)MT * DM_ * 4, hipMemcpyDeviceToDevice, stream);
  (void)hipMemcpyAsync((float*)d_out + (size_t)MT * DM_, pair_f, (size_t)PT * DP_ * 4, hipMemcpyDeviceToDevice, stream);
}

// Round 6
// 634.338 us; speedup vs baseline: 7.6206x; 1.2718x over previous
//
#include <hip/hip_runtime.h>
#include <hip/hip_bf16.h>

// MSA Transformer block: B=1, S=64, L=256, DM=256, DP=128, H=8, HT=4, NO=32
// Round 6: fused OPM (outer-product-mean + projection, no HBM intermediate).

#define S_ 64
#define L_ 256
#define DM_ 256
#define DP_ 128
#define H_ 8
#define HT_ 4
#define NO_ 32

typedef __hip_bfloat16 bf16;
typedef short short8 __attribute__((ext_vector_type(8)));
typedef float floatx4 __attribute__((ext_vector_type(4)));

__device__ __forceinline__ short f2bfs(float x) {
  union { float f; unsigned u; } v;
  v.f = x;
  unsigned r = (v.u + 0x7fffu + ((v.u >> 16) & 1u)) >> 16;
  return (short)r;
}

// ---------------- layernorm (1 wave per row) -> bf16 out ----------------
__global__ void k_ln(const float* __restrict__ src, bf16* __restrict__ dst,
                     const float* __restrict__ g, const float* __restrict__ bta, int D) {
  int row = blockIdx.x;
  const float* x = src + (size_t)row * D;
  bf16* y = dst + (size_t)row * D;
  int t = threadIdx.x; // 64
  float v[4];
  int cnt = 0;
  float sum = 0.f;
  for (int e = t; e < D; e += 64) { float xv = x[e]; v[cnt++] = xv; sum += xv; }
  #pragma unroll
  for (int o = 32; o; o >>= 1) sum += __shfl_down(sum, o);
  sum = __shfl(sum, 0);
  float mean = sum / D;
  float var = 0.f;
  for (int k = 0; k < cnt; k++) { float d = v[k] - mean; var += d * d; }
  #pragma unroll
  for (int o = 32; o; o >>= 1) var += __shfl_down(var, o);
  var = __shfl(var, 0);
  float rstd = rsqrtf(var / D + 1e-5f);
  cnt = 0;
  for (int e = t; e < D; e += 64)
    y[e] = __float2bfloat16((v[cnt++] - mean) * rstd * g[e] + bta[e]);
}

// ---------------- weight transpose+convert: W[K,N] f32 -> Wt[N,K] bf16 ----------------
__global__ void k_wt(const float* __restrict__ W, bf16* __restrict__ Wt, int K, int N) {
  __shared__ float tile[32][33];
  int k0 = blockIdx.x * 32, n0 = blockIdx.y * 32;
  int tid = threadIdx.x; // 256
  for (int e = tid; e < 1024; e += 256) {
    int r = e >> 5, c = e & 31;
    tile[r][c] = W[(size_t)(k0 + r) * N + (n0 + c)];
  }
  __syncthreads();
  for (int e = tid; e < 1024; e += 256) {
    int r = e >> 5, c = e & 31;
    Wt[(size_t)(n0 + r) * K + (k0 + c)] = __float2bfloat16(tile[c][r]);
  }
}

// ---------------- OPM transpose: a_buf[(s*L+i)*32+c] -> a_t[(i*32+c)*64+s] ----------------
__global__ void k_topm(const bf16* __restrict__ in, bf16* __restrict__ out) {
  __shared__ bf16 tile[64][34];
  int i = blockIdx.x; // L_
  int tid = threadIdx.x; // 256
  for (int e = tid; e < 64 * 32; e += 256) {
    int s = e >> 5, c = e & 31;
    tile[s][c] = in[(size_t)s * (L_ * NO_) + i * NO_ + c];
  }
  __syncthreads();
  for (int e = tid; e < 64 * 32; e += 256) {
    int c = e >> 6, s = e & 63;
    out[((size_t)i * NO_ + c) * S_ + s] = tile[s][c];
  }
}

// ---------------- bf16 MFMA GEMM: C[M,N] = A[M,K] @ Wt[N,K]^T * scale + bias ----------------
template<int ACC, int RELU, int OUTBF>
__global__ void k_gemm(const bf16* __restrict__ A, const bf16* __restrict__ Wt,
                       const float* __restrict__ bias, float* __restrict__ Cf,
                       bf16* __restrict__ Cb, int M, int N, int K, float scale) {
  __shared__ short As[128 * 64];
  __shared__ short Bs[128 * 64];
  const int tid = threadIdx.x;
  const int m0 = blockIdx.y * 128, n0 = blockIdx.x * 128;
  const int w = tid >> 6, l = tid & 63;
  const int wm = (w >> 1) * 64, wn = (w & 1) * 64;
  const int lr = l & 15, lk = l >> 4;
  floatx4 acc[4][4] = {};
  const short* Ash = (const short*)A;
  const short* Bsh = (const short*)Wt;
  for (int k0 = 0; k0 < K; k0 += 64) {
    for (int e = tid; e < 1024; e += 256) {
      int r = e >> 3, kg = e & 7;
      short8 v = *(const short8*)(Ash + (size_t)(m0 + r) * K + k0 + kg * 8);
      *(short8*)(&As[r * 64 + ((kg ^ (r & 7)) * 8)]) = v;
    }
    for (int e = tid; e < 1024; e += 256) {
      int r = e >> 3, kg = e & 7;
      int n = n0 + r;
      short8 v = {0, 0, 0, 0, 0, 0, 0, 0};
      if (n < N) v = *(const short8*)(Bsh + (size_t)n * K + k0 + kg * 8);
      *(short8*)(&Bs[r * 64 + ((kg ^ (r & 7)) * 8)]) = v;
    }
    __syncthreads();
    #pragma unroll
    for (int kk = 0; kk < 2; kk++) {
      short8 af[4], bfr[4];
      #pragma unroll
      for (int mi = 0; mi < 4; mi++) {
        int row = wm + mi * 16 + lr;
        int kg = kk * 4 + lk;
        af[mi] = *(const short8*)(&As[row * 64 + ((kg ^ (row & 7)) * 8)]);
      }
      #pragma unroll
      for (int ni = 0; ni < 4; ni++) {
        int row = wn + ni * 16 + lr;
        int kg = kk * 4 + lk;
        bfr[ni] = *(const short8*)(&Bs[row * 64 + ((kg ^ (row & 7)) * 8)]);
      }
      #pragma unroll
      for (int mi = 0; mi < 4; mi++)
        #pragma unroll
        for (int ni = 0; ni < 4; ni++)
          acc[mi][ni] = __builtin_amdgcn_mfma_f32_16x16x32_bf16(af[mi], bfr[ni], acc[mi][ni], 0, 0, 0);
    }
    __syncthreads();
  }
  #pragma unroll
  for (int ni = 0; ni < 4; ni++) {
    int n = n0 + wn + ni * 16 + lr;
    if (n >= N) continue;
    float bv = bias ? bias[n] : 0.f;
    #pragma unroll
    for (int mi = 0; mi < 4; mi++) {
      int mbase = m0 + wm + mi * 16 + lk * 4;
      #pragma unroll
      for (int r = 0; r < 4; r++) {
        float v = acc[mi][ni][r] * scale + bv;
        if (RELU) v = fmaxf(v, 0.f);
        size_t idx = (size_t)(mbase + r) * N + n;
        if (OUTBF) Cb[idx] = __float2bfloat16(v);
        else { if (ACC) Cf[idx] += v; else Cf[idx] = v; }
      }
    }
  }
}

// ---------------- fused OPM: pair[i, j, :] += (outer(a_i,b_j)/S) @ W + bias ----------------
// Block = (jhalf, i). 4 waves. Per 32-j group: U[c][j,e] via MFMA from L2-hot
// a_t/b_t (global->reg), staged bf16 (scaled 1/64) into swizzled LDS [32][1024],
// then proj GEMM M=32,N=128,K=1024 with W frags from L2-hot op_out_wt.
__global__ __launch_bounds__(256) void k_opm_fused(
    const bf16* __restrict__ a_t, const bf16* __restrict__ b_t,
    const bf16* __restrict__ Wt, const float* __restrict__ bias,
    float* __restrict__ pair) {
  __shared__ short U[32 * 1024]; // 64 KB
  const int i = blockIdx.y;
  const int jhalf = blockIdx.x; // 0..1
  const int tid = threadIdx.x;
  const int w = tid >> 6, l = tid & 63;
  const int lr = l & 15, lk = l >> 4;
  const short* at = (const short*)a_t;
  const short* bt = (const short*)b_t;
  const short* wt = (const short*)Wt;

  // preload A fragments: a_t rows (i*32 + mt*16 + lr), k = ks*32 + lk*8
  short8 af[2][2];
  #pragma unroll
  for (int mt = 0; mt < 2; mt++)
    #pragma unroll
    for (int ks = 0; ks < 2; ks++)
      af[mt][ks] = *(const short8*)(at + ((size_t)i * 32 + mt * 16 + lr) * 64 + ks * 32 + lk * 8);

  for (int grp = 0; grp < 4; grp++) {
    // ---- U phase: 2 subchunks of 16 j each ----
    #pragma unroll
    for (int sc = 0; sc < 2; sc++) {
      floatx4 uacc[2][8] = {};
      const size_t rowbase = ((size_t)(jhalf * 128 + grp * 32 + sc * 16) << 5) + w * 128;
      #pragma unroll
      for (int ks = 0; ks < 2; ks++)
        #pragma unroll
        for (int nt = 0; nt < 8; nt++) {
          short8 bfr = *(const short8*)(bt + (rowbase + nt * 16 + lr) * 64 + ks * 32 + lk * 8);
          #pragma unroll
          for (int mt = 0; mt < 2; mt++)
            uacc[mt][nt] = __builtin_amdgcn_mfma_f32_16x16x32_bf16(af[mt][ks], bfr, uacc[mt][nt], 0, 0, 0);
        }
      // write U (scaled by 1/S) to LDS, swizzled 16B granules
      #pragma unroll
      for (int nt = 0; nt < 8; nt++) {
        int npos = w * 128 + nt * 16 + lr;
        int j32 = sc * 16 + (npos >> 5);
        int e = npos & 31;
        #pragma unroll
        for (int mt = 0; mt < 2; mt++)
          #pragma unroll
          for (int r = 0; r < 4; r++) {
            int c = mt * 16 + lk * 4 + r;
            int ce = c * 32 + e;
            int g = ce >> 3;
            U[j32 * 1024 + ((g ^ (j32 & 7)) << 3) + (ce & 7)] = f2bfs(uacc[mt][nt][r] * 0.015625f);
          }
      }
    }
    __syncthreads();
    // ---- proj phase: pair[i, jbase..jbase+31, :] += U @ W + bias ----
    floatx4 pacc[2][2] = {};
    #pragma unroll 4
    for (int ks = 0; ks < 32; ks++) {
      short8 afp[2];
      #pragma unroll
      for (int mt = 0; mt < 2; mt++) {
        int row = mt * 16 + lr;
        int g = ks * 4 + lk;
        afp[mt] = *(const short8*)(&U[row * 1024 + ((g ^ (row & 7)) << 3)]);
      }
      #pragma unroll
      for (int ntl = 0; ntl < 2; ntl++) {
        int d = (w * 2 + ntl) * 16 + lr;
        short8 bfr = *(const short8*)(wt + (size_t)d * 1024 + ks * 32 + lk * 8);
        #pragma unroll
        for (int mt = 0; mt < 2; mt++)
          pacc[mt][ntl] = __builtin_amdgcn_mfma_f32_16x16x32_bf16(afp[mt], bfr, pacc[mt][ntl], 0, 0, 0);
      }
    }
    int jbase = jhalf * 128 + grp * 32;
    #pragma unroll
    for (int ntl = 0; ntl < 2; ntl++) {
      int d = (w * 2 + ntl) * 16 + lr;
      float bv = bias[d];
      #pragma unroll
      for (int mt = 0; mt < 2; mt++)
        #pragma unroll
        for (int r = 0; r < 4; r++) {
          int j = jbase + mt * 16 + lk * 4 + r;
          pair[((size_t)i * L_ + j) * DP_ + d] += pacc[mt][ntl][r] + bv;
        }
    }
    __syncthreads();
  }
}

// ---------------- MFMA attention: one (lead, head, 64-row chunk) per block ----------------
template<int N>
__global__ __launch_bounds__(256) void k_attn_mfma(
    const bf16* __restrict__ qkv, bf16* __restrict__ out, int dmodel,
    int tokStride, int leadStride, int otokStride, int oleadStride, float scale) {
  constexpr int NT = N / 16;   // S col-tiles per wave
  constexpr int NK = N / 32;   // PV k-steps
  constexpr int REGA = (64 * N > N * 32 + 2048) ? 64 * N : N * 32 + 2048;
  __shared__ short ldsA[REGA];
  __shared__ short Vt[N * 32];
  short* Ks = ldsA;            // [kslot][N][8]
  short* Qs = ldsA + N * 32;   // [kslot][64][8]
  short* P  = ldsA;            // [kstep][kslot][64][8]

  const int nIC = N / 64;
  const int lead = blockIdx.x / nIC, ic = blockIdx.x - lead * nIC;
  const int h = blockIdx.y;
  const short* base = (const short*)qkv + (size_t)lead * leadStride;
  const int qoff = h * 32, koff = dmodel + h * 32, voff = 2 * dmodel + h * 32;
  const int tid = threadIdx.x;
  const int l = tid & 63, w = tid >> 6;
  const int lr = l & 15, lk = l >> 4;

  for (int e = tid; e < N * 4; e += 256) {
    int j = e >> 2, kg = e & 3;
    short8 v = *(const short8*)(base + (size_t)j * tokStride + koff + kg * 8);
    *(short8*)(&Ks[(kg * N + j) * 8]) = v;
  }
  for (int e = tid; e < 256; e += 256) {
    int r = e >> 2, kg = e & 3;
    short8 v = *(const short8*)(base + (size_t)(ic * 64 + r) * tokStride + qoff + kg * 8);
    *(short8*)(&Qs[(kg * 64 + r) * 8]) = v;
  }
  for (int e = tid; e < N * 32; e += 256) {
    int j = e >> 5, d = e & 31;
    Vt[((j >> 5) * 4 + ((j >> 3) & 3)) * 256 + d * 8 + (j & 7)] = base[(size_t)j * tokStride + voff + d];
  }
  __syncthreads();

  short8 aq = *(const short8*)(&Qs[(lk * 64 + w * 16 + lr) * 8]);
  floatx4 sa[NT];
  #pragma unroll
  for (int t = 0; t < NT; t++) {
    short8 bk = *(const short8*)(&Ks[(lk * N + t * 16 + lr) * 8]);
    floatx4 z = {0.f, 0.f, 0.f, 0.f};
    sa[t] = __builtin_amdgcn_mfma_f32_16x16x32_bf16(aq, bk, z, 0, 0, 0);
  }

  float mrow[4] = {-1e30f, -1e30f, -1e30f, -1e30f};
  #pragma unroll
  for (int t = 0; t < NT; t++)
    #pragma unroll
    for (int r = 0; r < 4; r++) {
      float s = fminf(fmaxf(sa[t][r] * scale, -50.f), 50.f);
      sa[t][r] = s;
      mrow[r] = fmaxf(mrow[r], s);
    }
  #pragma unroll
  for (int o = 1; o <= 8; o <<= 1)
    #pragma unroll
    for (int r = 0; r < 4; r++) mrow[r] = fmaxf(mrow[r], __shfl_xor(mrow[r], o));
  float srow[4] = {0.f, 0.f, 0.f, 0.f};
  #pragma unroll
  for (int t = 0; t < NT; t++)
    #pragma unroll
    for (int r = 0; r < 4; r++) {
      float p = __expf(sa[t][r] - mrow[r]);
      sa[t][r] = p;
      srow[r] += p;
    }
  #pragma unroll
  for (int o = 1; o <= 8; o <<= 1)
    #pragma unroll
    for (int r = 0; r < 4; r++) srow[r] += __shfl_xor(srow[r], o);
  float inv[4];
  #pragma unroll
  for (int r = 0; r < 4; r++) inv[r] = 1.f / srow[r];

  __syncthreads();

  #pragma unroll
  for (int t = 0; t < NT; t++) {
    int c = t * 16 + lr;
    int kstep = c >> 5, kslot = (c >> 3) & 3, u = c & 7;
    #pragma unroll
    for (int r = 0; r < 4; r++) {
      int row = w * 16 + lk * 4 + r;
      P[((kstep * 4 + kslot) * 64 + row) * 8 + u] = f2bfs(sa[t][r] * inv[r]);
    }
  }
  __syncthreads();

  floatx4 oacc[2] = {{0.f,0.f,0.f,0.f},{0.f,0.f,0.f,0.f}};
  #pragma unroll
  for (int ks = 0; ks < NK; ks++) {
    short8 ap = *(const short8*)(&P[((ks * 4 + lk) * 64 + w * 16 + lr) * 8]);
    #pragma unroll
    for (int ct = 0; ct < 2; ct++) {
      short8 bv = *(const short8*)(&Vt[((ks * 4 + lk) * 32 + ct * 16 + lr) * 8]);
      oacc[ct] = __builtin_amdgcn_mfma_f32_16x16x32_bf16(ap, bv, oacc[ct], 0, 0, 0);
    }
  }
  bf16* ob = out + (size_t)lead * oleadStride + h * 32;
  #pragma unroll
  for (int ct = 0; ct < 2; ct++)
    #pragma unroll
    for (int r = 0; r < 4; r++) {
      int tok = ic * 64 + w * 16 + lk * 4 + r;
      ob[(size_t)tok * otokStride + ct * 16 + lr] = __float2bfloat16(oacc[ct][r]);
    }
}

extern "C" void kernel_launch(void* const* d_in, const int* in_sizes, int n_in,
                              void* d_out, int out_size, void* d_ws, size_t ws_size,
                              hipStream_t stream) {
  const float* msa_in    = (const float*)d_in[0];
  const float* pair_in   = (const float*)d_in[1];
  const float* row_ng    = (const float*)d_in[2];
  const float* row_nb    = (const float*)d_in[3];
  const float* row_qkv_w = (const float*)d_in[4];
  const float* row_qkv_b = (const float*)d_in[5];
  const float* row_out_w = (const float*)d_in[6];
  const float* row_out_b = (const float*)d_in[7];
  const float* col_ng    = (const float*)d_in[8];
  const float* col_nb    = (const float*)d_in[9];
  const float* col_qkv_w = (const float*)d_in[10];
  const float* col_qkv_b = (const float*)d_in[11];
  const float* col_out_w = (const float*)d_in[12];
  const float* col_out_b = (const float*)d_in[13];
  const float* ff_ng     = (const float*)d_in[14];
  const float* ff_nb     = (const float*)d_in[15];
  const float* ff_w1     = (const float*)d_in[16];
  const float* ff_b1     = (const float*)d_in[17];
  const float* ff_w2     = (const float*)d_in[18];
  const float* ff_b2     = (const float*)d_in[19];
  const float* op_ng     = (const float*)d_in[20];
  const float* op_nb     = (const float*)d_in[21];
  const float* op_a_w    = (const float*)d_in[22];
  const float* op_a_b    = (const float*)d_in[23];
  const float* op_b_w    = (const float*)d_in[24];
  const float* op_b_b    = (const float*)d_in[25];
  const float* op_out_w  = (const float*)d_in[26];
  const float* op_out_b  = (const float*)d_in[27];
  const float* tri_ng    = (const float*)d_in[28];
  const float* tri_nb    = (const float*)d_in[29];
  const float* tri_qkv_w = (const float*)d_in[30];
  const float* tri_qkv_b = (const float*)d_in[31];
  const float* tri_out_w = (const float*)d_in[32];
  const float* tri_out_b = (const float*)d_in[33];

  const int MT = S_ * L_;   // 16384
  const int PT = L_ * L_;   // 65536

  // ---- arena (byte offsets) ----
  char* ws = (char*)d_ws;
  float* msa_f  = (float*)(ws);                    // 16 MB
  float* pair_f = (float*)(ws + 16777216);         // 32 MB
  char*  X      = ws + 50331648;                   // 48 MB scratch (qkv bf16 / ffh bf16)
  bf16*  ln_b   = (bf16*)(ws + 100663296);         // 16 MB
  bf16*  ao_b   = (bf16*)(ws + 117440512);         // 16 MB
  bf16*  a_buf  = (bf16*)(ws + 134217728);         // 1 MB
  bf16*  b_buf  = (bf16*)(ws + 135266304);         // 1 MB
  bf16*  a_t    = (bf16*)(ws + 136314880);         // 1 MB
  bf16*  b_t    = (bf16*)(ws + 137363456);         // 1 MB
  bf16*  wts    = (bf16*)(ws + 138412032);         // ~2.6 MB

  bf16* row_qkv_wt = wts;                 // 768*256
  bf16* col_qkv_wt = row_qkv_wt + 196608;
  bf16* row_out_wt = col_qkv_wt + 196608; // 256*256
  bf16* col_out_wt = row_out_wt + 65536;
  bf16* ff_w1t     = col_out_wt + 65536;  // 1024*256
  bf16* ff_w2t     = ff_w1t + 262144;     // 256*1024
  bf16* op_a_wt    = ff_w2t + 262144;     // 32*256
  bf16* op_b_wt    = op_a_wt + 8192;
  bf16* op_out_wt  = op_b_wt + 8192;      // 128*1024
  bf16* tri_qkv_wt = op_out_wt + 131072;  // 384*128
  bf16* tri_out_wt = tri_qkv_wt + 49152;  // 128*128

  bf16* qkv_bf = (bf16*)X;   // row/col: 25MB; tri: 48MB
  bf16* ffh    = (bf16*)X;

  const float scale = 0.17677669529663687f; // 1/sqrt(32)

  // residual streams
  (void)hipMemcpyAsync(msa_f, msa_in, (size_t)MT * DM_ * 4, hipMemcpyDeviceToDevice, stream);
  (void)hipMemcpyAsync(pair_f, pair_in, (size_t)PT * DP_ * 4, hipMemcpyDeviceToDevice, stream);

  // weight transpose+convert (W[K,N] -> Wt[N,K] bf16)
  k_wt<<<dim3(256 / 32, 768 / 32), 256, 0, stream>>>(row_qkv_w, row_qkv_wt, 256, 768);
  k_wt<<<dim3(256 / 32, 768 / 32), 256, 0, stream>>>(col_qkv_w, col_qkv_wt, 256, 768);
  k_wt<<<dim3(256 / 32, 256 / 32), 256, 0, stream>>>(row_out_w, row_out_wt, 256, 256);
  k_wt<<<dim3(256 / 32, 256 / 32), 256, 0, stream>>>(col_out_w, col_out_wt, 256, 256);
  k_wt<<<dim3(256 / 32, 1024 / 32), 256, 0, stream>>>(ff_w1, ff_w1t, 256, 1024);
  k_wt<<<dim3(1024 / 32, 256 / 32), 256, 0, stream>>>(ff_w2, ff_w2t, 1024, 256);
  k_wt<<<dim3(256 / 32, 32 / 32), 256, 0, stream>>>(op_a_w, op_a_wt, 256, 32);
  k_wt<<<dim3(256 / 32, 32 / 32), 256, 0, stream>>>(op_b_w, op_b_wt, 256, 32);
  k_wt<<<dim3(1024 / 32, 128 / 32), 256, 0, stream>>>(op_out_w, op_out_wt, 1024, 128);
  k_wt<<<dim3(128 / 32, 384 / 32), 256, 0, stream>>>(tri_qkv_w, tri_qkv_wt, 128, 384);
  k_wt<<<dim3(128 / 32, 128 / 32), 256, 0, stream>>>(tri_out_w, tri_out_wt, 128, 128);

  // ---- 1. row attention (attend over L) ----
  k_ln<<<MT, 64, 0, stream>>>(msa_f, ln_b, row_ng, row_nb, DM_);
  k_gemm<0,0,1><<<dim3(6, 128), 256, 0, stream>>>(ln_b, row_qkv_wt, row_qkv_b, nullptr, qkv_bf, MT, 768, 256, 1.f);
  k_attn_mfma<256><<<dim3(256, 8), 256, 0, stream>>>(qkv_bf, ao_b, DM_, 768, L_ * 768, DM_, L_ * DM_, scale);
  k_gemm<1,0,0><<<dim3(2, 128), 256, 0, stream>>>(ao_b, row_out_wt, row_out_b, msa_f, nullptr, MT, DM_, DM_, 1.f);

  // ---- 2. column attention (attend over S) ----
  k_ln<<<MT, 64, 0, stream>>>(msa_f, ln_b, col_ng, col_nb, DM_);
  k_gemm<0,0,1><<<dim3(6, 128), 256, 0, stream>>>(ln_b, col_qkv_wt, col_qkv_b, nullptr, qkv_bf, MT, 768, 256, 1.f);
  k_attn_mfma<64><<<dim3(256, 8), 256, 0, stream>>>(qkv_bf, ao_b, DM_, L_ * 768, 768, L_ * DM_, DM_, scale);
  k_gemm<1,0,0><<<dim3(2, 128), 256, 0, stream>>>(ao_b, col_out_wt, col_out_b, msa_f, nullptr, MT, DM_, DM_, 1.f);

  // ---- 3. feed-forward ----
  k_ln<<<MT, 64, 0, stream>>>(msa_f, ln_b, ff_ng, ff_nb, DM_);
  k_gemm<0,1,1><<<dim3(8, 128), 256, 0, stream>>>(ln_b, ff_w1t, ff_b1, nullptr, ffh, MT, 1024, 256, 1.f);
  k_gemm<1,0,0><<<dim3(2, 128), 256, 0, stream>>>(ffh, ff_w2t, ff_b2, msa_f, nullptr, MT, DM_, 1024, 1.f);

  // ---- 4. outer product mean -> pair (fused, no HBM intermediate) ----
  k_ln<<<MT, 64, 0, stream>>>(msa_f, ln_b, op_ng, op_nb, DM_);
  k_gemm<0,0,1><<<dim3(1, 128), 256, 0, stream>>>(ln_b, op_a_wt, op_a_b, nullptr, a_buf, MT, NO_, DM_, 1.f);
  k_gemm<0,0,1><<<dim3(1, 128), 256, 0, stream>>>(ln_b, op_b_wt, op_b_b, nullptr, b_buf, MT, NO_, DM_, 1.f);
  k_topm<<<L_, 256, 0, stream>>>(a_buf, a_t);
  k_topm<<<L_, 256, 0, stream>>>(b_buf, b_t);
  k_opm_fused<<<dim3(2, L_), 256, 0, stream>>>(a_t, b_t, op_out_wt, op_out_b, pair_f);

  // ---- 5. triangle attention (attend over last L) ----
  k_ln<<<PT, 64, 0, stream>>>(pair_f, ln_b, tri_ng, tri_nb, DP_);
  k_gemm<0,0,1><<<dim3(3, 512), 256, 0, stream>>>(ln_b, tri_qkv_wt, tri_qkv_b, nullptr, qkv_bf, PT, 384, DP_, 1.f);
  k_attn_mfma<256><<<dim3(1024, 4), 256, 0, stream>>>(qkv_bf, ao_b, DP_, 384, L_ * 384, DP_, L_ * DP_, scale);
  k_gemm<1,0,0><<<dim3(1, 512), 256, 0, stream>>>(ao_b, tri_out_wt, tri_out_b, pair_f, nullptr, PT, DP_, DP_, 1.f);

  // ---- 6. pack outputs (msa then pair) ----
  (void)hipMemcpyAsync(d_out, msa_f, (size_t)MT * DM_ * 4, hipMemcpyDeviceToDevice, stream);
  (void)hipMemcpyAsync((float*)d_out + (size_t)MT * DM_, pair_f, (size_t)PT * DP_ * 4, hipMemcpyDeviceToDevice, stream);
}